// Round 9
// baseline (383.932 us; speedup 1.0000x reference)
//
#include <hip/hip_runtime.h>

// ---------------------------------------------------------------------------
// Swin block: LN1 -> shift+window -> QKV -> win-attn(+relbias+mask) -> proj
//             -> reverse+residual -> LN2 -> MLP1(GELU) -> MLP2 + residual
// B=16 H=W=64 C=256 WS=8 SHIFT=4 HEADS=8 HD=32 N=64 HID=1024
// Round 9: K=256 GEMMs -> persistent-B kernel (pgemm): B[128][256] staged in
//          LDS ONCE per block, block loops over m-tiles staging only A[64][256]
//          (dbuf). 1 barrier per m-tile (was 16), 3.2x less staging traffic.
//          R6-R8 invariant: all GEMMs ~88us regardless of occupancy/pipelining
//          -> staging pipe saturated; this attacks staged bytes directly.
//          MLP2 (K=1024) keeps the R8 tile kernel.
// ---------------------------------------------------------------------------

typedef __attribute__((ext_vector_type(8))) short bf16x8;
typedef __attribute__((ext_vector_type(4))) float f32x4;
typedef __attribute__((ext_vector_type(16))) float f32x16;

__device__ __forceinline__ float bf2f(unsigned short h) {
    union { unsigned int u; float f; } c; c.u = ((unsigned int)h) << 16; return c.f;
}
__device__ __forceinline__ unsigned short f2bf(float f) {
    union { float f; unsigned int u; } c; c.f = f;
    unsigned int u = c.u;
    return (unsigned short)((u + 0x7FFFu + ((u >> 16) & 1u)) >> 16);
}
__device__ __forceinline__ unsigned int cvtpk_bf16(float lo, float hi) {
    unsigned int r;
    asm volatile("v_cvt_pk_bf16_f32 %0, %1, %2" : "=v"(r) : "v"(lo), "v"(hi));
    return r;
}
__device__ __forceinline__ void perm32swap(unsigned int& a, unsigned int& b) {
    asm volatile("v_permlane32_swap_b32 %0, %1" : "+v"(a), "+v"(b));
}
// window-order row (b, wi, wj, r, cc) -> pixel-order row (b, hp, wp).
__device__ __forceinline__ int remap_row(int row) {
    int b  = row >> 12;
    int w6 = (row >> 6) & 63;
    int n  = row & 63;
    int hp = (((w6 >> 3) << 3) + (n >> 3) + 4) & 63;
    int wp = (((w6 & 7) << 3) + (n & 7) + 4) & 63;
    return (b << 12) | (hp << 6) | wp;
}
// gelu(v) = v * sigmoid(2c(v + 0.044715 v^3)), c = sqrt(2/pi)
__device__ __forceinline__ float gelu_f(float v) {
    float u = 1.5957691216057308f * (v + 0.044715f * v * v * v);
    return v / (1.0f + __expf(-u));
}
__device__ __forceinline__ void gload16(const unsigned short* g, unsigned short* l) {
    __builtin_amdgcn_global_load_lds(
        (const __attribute__((address_space(1))) void*)g,
        (__attribute__((address_space(3))) void*)l, 16, 0, 0);
}

// ---- LayerNorm over C=256; one wave per row; optional gather remap --------
__global__ __launch_bounds__(256) void ln_kernel(
    const float* __restrict__ in, const float* __restrict__ g,
    const float* __restrict__ b, unsigned short* __restrict__ out, int remap)
{
    int wave = threadIdx.x >> 6, lane = threadIdx.x & 63;
    int row = (blockIdx.x << 2) + wave;
    int src = remap ? remap_row(row) : row;
    float4 xv = *(const float4*)(in + (size_t)src * 256 + (lane << 2));
    float s  = xv.x + xv.y + xv.z + xv.w;
    float ss = xv.x*xv.x + xv.y*xv.y + xv.z*xv.z + xv.w*xv.w;
#pragma unroll
    for (int off = 32; off; off >>= 1) {
        s  += __shfl_xor(s,  off, 64);
        ss += __shfl_xor(ss, off, 64);
    }
    float mu  = s * (1.0f / 256.0f);
    float inv = rsqrtf(ss * (1.0f / 256.0f) - mu * mu + 1e-5f);
    float4 gv = *(const float4*)(g + (lane << 2));
    float4 bv = *(const float4*)(b + (lane << 2));
    ushort4 o;
    o.x = f2bf((xv.x - mu) * inv * gv.x + bv.x);
    o.y = f2bf((xv.y - mu) * inv * gv.y + bv.y);
    o.z = f2bf((xv.z - mu) * inv * gv.z + bv.z);
    o.w = f2bf((xv.w - mu) * inv * gv.w + bv.w);
    *(ushort4*)(out + (size_t)row * 256 + (lane << 2)) = o;
}

// ---- prep: 4x weight transpose+bf16 convert, + rel-pos bias expand --------
__device__ __forceinline__ void convT_body(
    const float* __restrict__ in, unsigned short* __restrict__ out,
    int K, int N, int b, float (*t)[33], int tid)
{
    int kb = K >> 5;
    int bk = (b % kb) << 5;
    int bn = (b / kb) << 5;
    int r = tid >> 5, c = tid & 31;
#pragma unroll
    for (int i = 0; i < 4; ++i)
        t[r + i * 8][c] = in[(size_t)(bk + r + i * 8) * N + bn + c];
    __syncthreads();
#pragma unroll
    for (int i = 0; i < 4; ++i)
        out[(size_t)(bn + r + i * 8) * K + bk + c] = f2bf(t[c][r + i * 8]);
}

__global__ __launch_bounds__(256) void prep_kernel(
    const float* __restrict__ qkv_w, const float* __restrict__ proj_w,
    const float* __restrict__ w1, const float* __restrict__ w2,
    unsigned short* __restrict__ qkvT, unsigned short* __restrict__ prjT,
    unsigned short* __restrict__ w1T, unsigned short* __restrict__ w2T,
    const float* __restrict__ table, const int* __restrict__ relidx,
    float* __restrict__ bexp)
{
    __shared__ float t[32][33];
    const int b = blockIdx.x, tid = threadIdx.x;
    if      (b < 192) convT_body(qkv_w, qkvT, 256,  768, b,       t, tid);
    else if (b < 256) convT_body(proj_w, prjT, 256,  256, b - 192, t, tid);
    else if (b < 512) convT_body(w1,    w1T,  256, 1024, b - 256, t, tid);
    else if (b < 768) convT_body(w2,    w2T, 1024,  256, b - 512, t, tid);
    else {
        int i = (b - 768) * 256 + tid;       // 8*64*64 = 32768
        int head = i >> 12;
        int q = (i >> 6) & 63;
        int k = i & 63;
        bexp[i] = table[relidx[q * 64 + k] * 8 + head];
    }
}

// ---- persistent-B MFMA GEMM (K=256): A bf16 [65536,256], BT bf16 [N,256] --
// Block: 512 thr / 8 waves (2m x 4n of 32x32). B[128n][256k] in LDS once;
// loop over m-tiles (stride G), A[64][256] double-buffered; 1 barrier/m-tile.
// 16B-group XOR swizzle over 3 row bits (2-way-conflict floor).
template<int OUT_BF16, int DO_GELU, int RESID, int QSCALE>
__global__ __launch_bounds__(512, 2) void pgemm_kernel(
    const unsigned short* __restrict__ A, const unsigned short* __restrict__ BT,
    const float* __restrict__ bias, void* __restrict__ outp,
    const float* __restrict__ resid, int N, int G)
{
    __shared__ unsigned short Bl[128 * 256];     // 64 KB
    __shared__ unsigned short Al[2][64 * 256];   // 64 KB

    const int cpx = (int)gridDim.x >> 3;
    const int bid = ((int)blockIdx.x & 7) * cpx + ((int)blockIdx.x >> 3);
    const int ntile = bid / G;
    const int g     = bid % G;
    const int n0 = ntile << 7;

    const int tid  = threadIdx.x;
    const int lane = tid & 63;
    const int wid  = tid >> 6;
    const int wm = (wid >> 2) << 5;          // 0,32
    const int wn = (wid & 3) << 5;           // 0,32,64,96
    const int fr = lane & 15, fq = lane >> 4;

    // ---- stage B once: slot (r, p) holds logical kgroup (p&24)|((p^r)&7) ----
    {
        const unsigned short* Bg = BT + (size_t)n0 * 256;
#pragma unroll
        for (int i = 0; i < 8; ++i) {
            int s = tid + (i << 9);
            int r = s >> 5, p = s & 31;
            int lg = (p & 24) | ((p ^ r) & 7);
            gload16(Bg + (size_t)r * 256 + lg * 8, Bl + s * 8);
        }
    }
#define STAGE_A(buf, mt)                                                      \
    {                                                                         \
        const unsigned short* Ag_ = A + (size_t)(mt) * 64 * 256;              \
        _Pragma("unroll")                                                     \
        for (int i_ = 0; i_ < 4; ++i_) {                                      \
            int s_ = tid + (i_ << 9);                                         \
            int r_ = s_ >> 5, p_ = s_ & 31;                                   \
            int lg_ = (p_ & 24) | ((p_ ^ r_) & 7);                            \
            gload16(Ag_ + (size_t)r_ * 256 + lg_ * 8, Al[buf] + s_ * 8);      \
        }                                                                     \
    }
    STAGE_A(0, g);
    asm volatile("s_waitcnt vmcnt(0)" ::: "memory");
    __builtin_amdgcn_s_barrier();

    int buf = 0;
    for (int mt = g; mt < 1024; mt += G) {
        if (mt + G < 1024) STAGE_A(buf ^ 1, mt + G);   // overlap next-A with compute

        f32x4 acc[2][2] = {};
#pragma unroll
        for (int it = 0; it < 8; ++it) {
            bf16x8 af[2], bf[2];
#pragma unroll
            for (int i = 0; i < 2; ++i) {
                int ar = wm + i * 16 + fr;
                int kg = it * 4 + fq;
                int p  = (kg & 24) | ((kg ^ ar) & 7);
                af[i] = *(const bf16x8*)(Al[buf] + ar * 256 + p * 8);
            }
#pragma unroll
            for (int j = 0; j < 2; ++j) {
                int br = wn + j * 16 + fr;
                int kg = it * 4 + fq;
                int p  = (kg & 24) | ((kg ^ br) & 7);
                bf[j] = *(const bf16x8*)(Bl + br * 256 + p * 8);
            }
#pragma unroll
            for (int j = 0; j < 2; ++j)
#pragma unroll
                for (int i = 0; i < 2; ++i)
                    acc[j][i] = __builtin_amdgcn_mfma_f32_16x16x32_bf16(
                        bf[j], af[i], acc[j][i], 0, 0, 0);  // C^T (verified R6)
        }

        // ---- epilogue: row = mt*64 + wm + i*16 + fr; cols colbase..+3 -------
#pragma unroll
        for (int j = 0; j < 2; ++j) {
            const int colbase = n0 + wn + j * 16 + (fq << 2);
            const float4 b4 = *(const float4*)(bias + colbase);
#pragma unroll
            for (int i = 0; i < 2; ++i) {
                const int row = (mt << 6) + wm + i * 16 + fr;
                float v0 = acc[j][i][0] + b4.x;
                float v1 = acc[j][i][1] + b4.y;
                float v2 = acc[j][i][2] + b4.z;
                float v3 = acc[j][i][3] + b4.w;
                if (QSCALE && colbase < 256) {
                    v0 *= 0.17677669529663687f; v1 *= 0.17677669529663687f;
                    v2 *= 0.17677669529663687f; v3 *= 0.17677669529663687f;
                }
                if (DO_GELU) {
                    v0 = gelu_f(v0); v1 = gelu_f(v1); v2 = gelu_f(v2); v3 = gelu_f(v3);
                }
                if (OUT_BF16) {
                    uint2 pp;
                    pp.x = cvtpk_bf16(v0, v1);
                    pp.y = cvtpk_bf16(v2, v3);
                    *(uint2*)((unsigned short*)outp + (size_t)row * N + colbase) = pp;
                } else {
                    const int orow = (RESID == 2) ? remap_row(row) : row;
                    float4 o4;
                    if (RESID) {
                        const float4 r4 = *(const float4*)(resid + (size_t)orow * N + colbase);
                        o4.x = v0 + r4.x; o4.y = v1 + r4.y;
                        o4.z = v2 + r4.z; o4.w = v3 + r4.w;
                    } else {
                        o4.x = v0; o4.y = v1; o4.z = v2; o4.w = v3;
                    }
                    *(float4*)((float*)outp + (size_t)orow * N + colbase) = o4;
                }
            }
        }

        asm volatile("s_waitcnt vmcnt(0)" ::: "memory");  // next-A landed
        __builtin_amdgcn_s_barrier();                     // safe to overwrite buf
        buf ^= 1;
    }
#undef STAGE_A
}

// ---- tile MFMA GEMM (used for MLP2, K=1024): as R8 ------------------------
template<int OUT_BF16, int DO_GELU, int RESID, int QSCALE>
__global__ __launch_bounds__(512, 4) void mgemm_kernel(
    const unsigned short* __restrict__ A, const unsigned short* __restrict__ BT,
    const float* __restrict__ bias, void* __restrict__ outp,
    const float* __restrict__ resid, int M, int N, int K)
{
    __shared__ unsigned short As[2][128 * 32];
    __shared__ unsigned short Bs[2][128 * 32];

    const int cpx = (int)gridDim.x >> 3;
    const int bid = ((int)blockIdx.x & 7) * cpx + ((int)blockIdx.x >> 3);

    const int nb = N >> 7;
    const int m0 = (bid / nb) << 7;
    const int n0 = (bid % nb) << 7;
    const int tid  = threadIdx.x;
    const int wid  = tid >> 6;
    const int lane = tid & 63;
    const int wm = (wid >> 1) << 5;
    const int wn = (wid & 1) << 6;

    const unsigned short* Ag = A  + (size_t)m0 * K;
    const unsigned short* Bg = BT + (size_t)n0 * K;
    const size_t ra = (size_t)(tid >> 2) * K + (((tid & 3) ^ ((tid >> 2) & 3)) << 3);

    f32x4 acc[4][2] = {};
    const int fr = lane & 15;
    const int fq = lane >> 4;
    const int axor = ((fq ^ (fr & 3)) << 3);

#define STAGE(buf, kk)                                                        \
    {                                                                         \
        gload16(Ag + ra + (kk), As[buf] + tid * 8);                           \
        gload16(Bg + ra + (kk), Bs[buf] + tid * 8);                           \
    }
    STAGE(0, 0);
    STAGE(1, 32);
    asm volatile("s_waitcnt vmcnt(2)" ::: "memory");
    __builtin_amdgcn_s_barrier();
    __builtin_amdgcn_sched_barrier(0);

    for (int k0 = 0; k0 < K; k0 += 32) {
        const int cur = (k0 >> 5) & 1;
        bf16x8 af[2], bfr[4];
#pragma unroll
        for (int i = 0; i < 2; ++i)
            af[i] = *(const bf16x8*)(As[cur] + (wm + i * 16 + fr) * 32 + axor);
#pragma unroll
        for (int j = 0; j < 4; ++j)
            bfr[j] = *(const bf16x8*)(Bs[cur] + (wn + j * 16 + fr) * 32 + axor);
#pragma unroll
        for (int j = 0; j < 4; ++j)
#pragma unroll
            for (int i = 0; i < 2; ++i)
                acc[j][i] = __builtin_amdgcn_mfma_f32_16x16x32_bf16(
                    bfr[j], af[i], acc[j][i], 0, 0, 0);

        if (k0 + 32 < K) {
            __builtin_amdgcn_s_barrier();
            if (k0 + 64 < K) {
                STAGE(cur, k0 + 64);
                asm volatile("s_waitcnt vmcnt(2)" ::: "memory");
            } else {
                asm volatile("s_waitcnt vmcnt(0)" ::: "memory");
            }
            __builtin_amdgcn_s_barrier();
            __builtin_amdgcn_sched_barrier(0);
        }
    }
#undef STAGE

#pragma unroll
    for (int j = 0; j < 4; ++j) {
        const int colbase = n0 + wn + j * 16 + (fq << 2);
        const float4 b4 = *(const float4*)(bias + colbase);
#pragma unroll
        for (int i = 0; i < 2; ++i) {
            const int row = m0 + wm + i * 16 + fr;
            float v0 = acc[j][i][0] + b4.x;
            float v1 = acc[j][i][1] + b4.y;
            float v2 = acc[j][i][2] + b4.z;
            float v3 = acc[j][i][3] + b4.w;
            if (QSCALE && colbase < 256) {
                v0 *= 0.17677669529663687f; v1 *= 0.17677669529663687f;
                v2 *= 0.17677669529663687f; v3 *= 0.17677669529663687f;
            }
            if (DO_GELU) {
                v0 = gelu_f(v0); v1 = gelu_f(v1); v2 = gelu_f(v2); v3 = gelu_f(v3);
            }
            if (OUT_BF16) {
                uint2 pp;
                pp.x = cvtpk_bf16(v0, v1);
                pp.y = cvtpk_bf16(v2, v3);
                *(uint2*)((unsigned short*)outp + (size_t)row * N + colbase) = pp;
            } else {
                const int orow = (RESID == 2) ? remap_row(row) : row;
                float4 o4;
                if (RESID) {
                    const float4 r4 = *(const float4*)(resid + (size_t)orow * N + colbase);
                    o4.x = v0 + r4.x; o4.y = v1 + r4.y;
                    o4.z = v2 + r4.z; o4.w = v3 + r4.w;
                } else {
                    o4.x = v0; o4.y = v1; o4.z = v2; o4.w = v3;
                }
                *(float4*)((float*)outp + (size_t)orow * N + colbase) = o4;
            }
        }
    }
}

// ---- MFMA window attention: one wave per (window, head) -------------------
__global__ __launch_bounds__(64, 3) void attn_kernel(
    const unsigned short* __restrict__ qkv,
    const float* __restrict__ bexp,
    unsigned short* __restrict__ out)
{
    __shared__ unsigned short VT[2048];
    const int bid  = blockIdx.x;
    const int widx = bid & 1023;
    const int head = bid >> 10;
    const int l  = threadIdx.x;
    const int lo = l & 31, hi = l >> 5;

    const unsigned short* base = qkv + (size_t)widx * 64 * 768;

#pragma unroll
    for (int c = 0; c < 4; ++c) {
        union { bf16x8 v; unsigned short s[8]; } u;
        u.v = *(const bf16x8*)(base + (size_t)l * 768 + 512 + head * 32 + c * 8);
#pragma unroll
        for (int e = 0; e < 8; ++e) {
            int d = c * 8 + e;
            int wb = ((d * 64 + l) * 2) ^ ((d & 7) << 4);
            *(unsigned short*)((char*)VT + wb) = u.s[e];
        }
    }

    f32x16 acc[2][2] = {};
#pragma unroll
    for (int kd = 0; kd < 2; ++kd) {
        const int coff = head * 32 + kd * 16 + hi * 8;
        bf16x8 kf0 = *(const bf16x8*)(base + (size_t)lo        * 768 + 256 + coff);
        bf16x8 kf1 = *(const bf16x8*)(base + (size_t)(32 + lo) * 768 + 256 + coff);
        bf16x8 qf0 = *(const bf16x8*)(base + (size_t)lo        * 768 + coff);
        bf16x8 qf1 = *(const bf16x8*)(base + (size_t)(32 + lo) * 768 + coff);
        acc[0][0] = __builtin_amdgcn_mfma_f32_32x32x16_bf16(kf0, qf0, acc[0][0], 0, 0, 0);
        acc[0][1] = __builtin_amdgcn_mfma_f32_32x32x16_bf16(kf0, qf1, acc[0][1], 0, 0, 0);
        acc[1][0] = __builtin_amdgcn_mfma_f32_32x32x16_bf16(kf1, qf0, acc[1][0], 0, 0, 0);
        acc[1][1] = __builtin_amdgcn_mfma_f32_32x32x16_bf16(kf1, qf1, acc[1][1], 0, 0, 0);
    }

#pragma unroll
    for (int qb = 0; qb < 2; ++qb) {
        const float* bq = bexp + head * 4096 + (qb * 32 + lo) * 64;
#pragma unroll
        for (int kb = 0; kb < 2; ++kb)
#pragma unroll
            for (int j = 0; j < 4; ++j) {
                float4 b4 = *(const float4*)(bq + kb * 32 + j * 8 + hi * 4);
                acc[kb][qb][4 * j + 0] += b4.x;
                acc[kb][qb][4 * j + 1] += b4.y;
                acc[kb][qb][4 * j + 2] += b4.z;
                acc[kb][qb][4 * j + 3] += b4.w;
            }
    }

    const int w6 = widx & 63;
    if (((w6 >> 3) == 7) || ((w6 & 7) == 7)) {
#pragma unroll
        for (int qb = 0; qb < 2; ++qb) {
            int nq = qb * 32 + lo;
            int phq = ((w6 >> 3) << 3) + (nq >> 3), pwq = ((w6 & 7) << 3) + (nq & 7);
            int rq = ((phq < 56) ? 0 : ((phq < 60) ? 1 : 2)) * 3
                   + ((pwq < 56) ? 0 : ((pwq < 60) ? 1 : 2));
#pragma unroll
            for (int kb = 0; kb < 2; ++kb)
#pragma unroll
                for (int r = 0; r < 16; ++r) {
                    int nk = kb * 32 + (r & 3) + 8 * (r >> 2) + 4 * hi;
                    int phk = ((w6 >> 3) << 3) + (nk >> 3), pwk = ((w6 & 7) << 3) + (nk & 7);
                    int rk = ((phk < 56) ? 0 : ((phk < 60) ? 1 : 2)) * 3
                           + ((pwk < 56) ? 0 : ((pwk < 60) ? 1 : 2));
                    if (rk != rq) acc[kb][qb][r] -= 100.0f;
                }
        }
    }

#pragma unroll
    for (int qb = 0; qb < 2; ++qb) {
        float mx = acc[0][qb][0];
#pragma unroll
        for (int r = 1; r < 16; ++r) mx = fmaxf(mx, acc[0][qb][r]);
#pragma unroll
        for (int r = 0; r < 16; ++r) mx = fmaxf(mx, acc[1][qb][r]);
        mx = fmaxf(mx, __shfl_xor(mx, 32, 64));
        float sum = 0.f;
#pragma unroll
        for (int kb = 0; kb < 2; ++kb)
#pragma unroll
            for (int r = 0; r < 16; ++r) {
                float e = __expf(acc[kb][qb][r] - mx);
                acc[kb][qb][r] = e;
                sum += e;
            }
        sum += __shfl_xor(sum, 32, 64);
        float inv = 1.0f / sum;
#pragma unroll
        for (int kb = 0; kb < 2; ++kb)
#pragma unroll
            for (int r = 0; r < 16; ++r) acc[kb][qb][r] *= inv;
    }

    f32x16 o[2] = {};
#pragma unroll
    for (int ks = 0; ks < 4; ++ks) {
        const int s8 = (ks & 1) * 8, kb = ks >> 1;
        const int rb = ((lo * 64 + 16 * ks + 8 * hi) * 2) ^ ((lo & 7) << 4);
        bf16x8 vb = *(const bf16x8*)((const char*)VT + rb);
#pragma unroll
        for (int qb = 0; qb < 2; ++qb) {
            unsigned int a0 = cvtpk_bf16(acc[kb][qb][s8 + 0], acc[kb][qb][s8 + 1]);
            unsigned int b0 = cvtpk_bf16(acc[kb][qb][s8 + 4], acc[kb][qb][s8 + 5]);
            unsigned int a1 = cvtpk_bf16(acc[kb][qb][s8 + 2], acc[kb][qb][s8 + 3]);
            unsigned int b1 = cvtpk_bf16(acc[kb][qb][s8 + 6], acc[kb][qb][s8 + 7]);
            perm32swap(a0, b0);
            perm32swap(a1, b1);
            union { unsigned int u[4]; bf16x8 v; } w;
            w.u[0] = a0; w.u[1] = a1; w.u[2] = b0; w.u[3] = b1;
            o[qb] = __builtin_amdgcn_mfma_f32_32x32x16_bf16(w.v, vb, o[qb], 0, 0, 0);
        }
    }

    unsigned short* ob = out + (size_t)widx * 64 * 256 + head * 32 + lo;
#pragma unroll
    for (int qb = 0; qb < 2; ++qb)
#pragma unroll
        for (int r = 0; r < 16; ++r) {
            int q = qb * 32 + (r & 3) + 8 * (r >> 2) + 4 * hi;
            ob[(size_t)q * 256] = f2bf(o[qb][r]);
        }
}

// ---------------------------------------------------------------------------
extern "C" void kernel_launch(void* const* d_in, const int* in_sizes, int n_in,
                              void* d_out, int out_size, void* d_ws, size_t ws_size,
                              hipStream_t stream)
{
    const float* x      = (const float*)d_in[0];
    const float* ln1_g  = (const float*)d_in[1];
    const float* ln1_b  = (const float*)d_in[2];
    const float* qkv_w  = (const float*)d_in[3];
    const float* qkv_b  = (const float*)d_in[4];
    const float* proj_w = (const float*)d_in[5];
    const float* proj_b = (const float*)d_in[6];
    const float* table  = (const float*)d_in[7];
    const float* ln2_g  = (const float*)d_in[8];
    const float* ln2_b  = (const float*)d_in[9];
    const float* w1     = (const float*)d_in[10];
    const float* b1     = (const float*)d_in[11];
    const float* w2     = (const float*)d_in[12];
    const float* b2     = (const float*)d_in[13];
    const int*   relidx = (const int*)d_in[14];
    float* out = (float*)d_out;

    char* w = (char*)d_ws;
    unsigned short* xw   = (unsigned short*)w;                      // 32MB (xw -> attn_out -> ln2out)
    unsigned short* qkvb = (unsigned short*)(w + (32u << 20));      // 128MB (qkv 96MB -> mlp hidden 128MB)
    float*          h2   = (float*)(w + (160u << 20));              // 64MB
    float*          bexp = (float*)(w + (224u << 20));              // 128KB
    unsigned short* qkvT = (unsigned short*)(w + (224u << 20) + (128u << 10)); // 384KB
    unsigned short* prjT = qkvT + 768 * 256;                        // 128KB
    unsigned short* w1T  = prjT + 256 * 256;                        // 512KB
    unsigned short* w2T  = w1T + 1024 * 256;                        // 512KB

    // 0. weight transposes + bf16 convert + rel-pos bias expand (one kernel)
    prep_kernel<<<896, 256, 0, stream>>>(qkv_w, proj_w, w1, w2,
                                         qkvT, prjT, w1T, w2T,
                                         table, relidx, bexp);
    // 1. LN1 + cyclic shift + window partition (gather) -> xw bf16 [65536,256]
    ln_kernel<<<16384, 256, 0, stream>>>(x, ln1_g, ln1_b, xw, 1);
    // 2. QKV GEMM (q cols pre-scaled by hd^-0.5) -> qkvb bf16 [65536,768]
    pgemm_kernel<1, 0, 0, 1><<<6 * 64, 512, 0, stream>>>(xw, qkvT, qkv_b, (void*)qkvb,
                                                         nullptr, 768, 64);
    // 3. MFMA window attention -> attn_out (reuse xw) bf16 [65536,256]
    attn_kernel<<<8192, 64, 0, stream>>>(qkvb, bexp, xw);
    // 4. proj GEMM + window-reverse/unshift scatter + residual(x) -> h2 f32
    pgemm_kernel<0, 0, 2, 0><<<2 * 128, 512, 0, stream>>>(xw, prjT, proj_b, (void*)h2,
                                                          x, 256, 128);
    // 5. LN2 -> ln2out (reuse xw) bf16
    ln_kernel<<<16384, 256, 0, stream>>>(h2, ln2_g, ln2_b, xw, 0);
    // 6. MLP1 GEMM + GELU -> hidden (reuse qkvb) bf16 [65536,1024]
    pgemm_kernel<1, 1, 0, 0><<<8 * 48, 512, 0, stream>>>(xw, w1T, b1, (void*)qkvb,
                                                         nullptr, 1024, 48);
    // 7. MLP2 GEMM + residual(h2) -> d_out f32 (K=1024: tile kernel)
    mgemm_kernel<0, 0, 1, 0><<<512 * 2, 512, 0, stream>>>(qkvb, w2T, b2, (void*)out,
                                                          h2, 65536, 256, 1024);
}